// Round 8
// baseline (119.910 us; speedup 1.0000x reference)
//
#include <hip/hip_runtime.h>
#include <hip/hip_bf16.h>
#include <math.h>

#define NN 4096
#define DD 1024
#define NCLS 128
#define TAU 0.5f
#define EPSV 1e-8f

typedef __bf16 bf16;
typedef __bf16 bf16x8 __attribute__((ext_vector_type(8)));
typedef __bf16 bf16x4 __attribute__((ext_vector_type(4)));
typedef float f32x4 __attribute__((ext_vector_type(4)));

__device__ __forceinline__ void gl2lds16(const void* g, void* l) {
    __builtin_amdgcn_global_load_lds(
        (const __attribute__((address_space(1))) void*)g,
        (__attribute__((address_space(3))) void*)l,
        16, 0, 0);
}

// K1: blocks 0..1023: per-row L2 norm -> normalized bf16 copy; zero rsum.
// block 1024: class stats (cnt, min-idx, 2nd-min-idx) + zero out.
__global__ __launch_bounds__(256) void k_prep(const float* __restrict__ X,
                                              bf16* __restrict__ Xn,
                                              float* __restrict__ rsum,
                                              const int* __restrict__ y,
                                              int* __restrict__ cnt,
                                              int* __restrict__ mn1,
                                              int* __restrict__ mn2,
                                              float* __restrict__ out) {
    if (blockIdx.x < 1024) {
        int w = threadIdx.x >> 6, lane = threadIdx.x & 63;
        int row = blockIdx.x * 4 + w;
        const float* xr = X + (size_t)row * DD;
        float4 v[4];
        float ss = 0.f;
#pragma unroll
        for (int c = 0; c < 4; ++c) {
            v[c] = *(const float4*)(xr + c * 256 + lane * 4);
            ss += v[c].x * v[c].x + v[c].y * v[c].y + v[c].z * v[c].z + v[c].w * v[c].w;
        }
#pragma unroll
        for (int m = 1; m < 64; m <<= 1) ss += __shfl_xor(ss, m, 64);
        float rn = 1.f / fmaxf(sqrtf(ss), EPSV);
        if (lane == 0) rsum[row] = 0.f;
#pragma unroll
        for (int c = 0; c < 4; ++c) {
            bf16x4 o;
            o.x = (bf16)(v[c].x * rn);
            o.y = (bf16)(v[c].y * rn);
            o.z = (bf16)(v[c].z * rn);
            o.w = (bf16)(v[c].w * rn);
            *(bf16x4*)(Xn + (size_t)row * DD + c * 256 + lane * 4) = o;
        }
    } else {
        __shared__ int sc[NCLS], s1[NCLS], s2[NCLS];
        int t = threadIdx.x;
        if (t < NCLS) { sc[t] = 0; s1[t] = 0x7fffffff; s2[t] = 0x7fffffff; }
        __syncthreads();
        int yv[16];
#pragma unroll
        for (int k = 0; k < 16; ++k) {
            int i = k * 256 + t;
            yv[k] = y[i];
            atomicAdd(&sc[yv[k]], 1);
            atomicMin(&s1[yv[k]], i);
        }
        __syncthreads();
#pragma unroll
        for (int k = 0; k < 16; ++k) {
            int i = k * 256 + t;
            if (s1[yv[k]] != i) atomicMin(&s2[yv[k]], i);
        }
        __syncthreads();
        if (t < NCLS) { cnt[t] = sc[t]; mn1[t] = s1[t]; mn2[t] = s2[t]; }
        if (t == 0) out[0] = 0.f;
    }
}

// K2: upper-triangle 128x128-tile bf16 MFMA gram, BK=32, DOUBLE-BUFFERED LDS
// (one barrier per stage; next stage's global_load_lds issued after the barrier
// so its latency is hidden behind the compute phase). Fused exp/mask epilogue;
// off-diagonal tiles also col-reduce (symmetry).
__global__ __launch_bounds__(256) void k_gemm(const bf16* __restrict__ Xn,
                                              const int* __restrict__ y,
                                              float* __restrict__ rowsum) {
    __shared__ __align__(16) bf16 As[2 * 128 * 32];
    __shared__ __align__(16) bf16 Bs[2 * 128 * 32];
    __shared__ int yA[128], yB[128];

    // decode linear block id -> (bi, bj), bi <= bj
    int id = blockIdx.x;
    float ff = sqrtf((float)(8 * id + 1));
    int bj = (int)((ff - 1.f) * 0.5f);
    if (bj * (bj + 1) / 2 > id) bj--;
    if ((bj + 1) * (bj + 2) / 2 <= id) bj++;
    int bi = id - bj * (bj + 1) / 2;
    const int rowA0 = bi * 128;
    const int rowB0 = bj * 128;
    const bool diag = (bi == bj);

    const int tid = threadIdx.x;
    if (tid < 128) yA[tid] = y[rowA0 + tid];
    else           yB[tid - 128] = y[rowB0 + tid - 128];

    const int lane = tid & 63;
    const int w = tid >> 6;
    const int wm = w & 1, wn = w >> 1;     // 2x2 waves -> each wave 64x64
    const int lr = lane >> 4, lc = lane & 15;

    f32x4 acc[4][4];
#pragma unroll
    for (int i = 0; i < 4; ++i)
#pragma unroll
        for (int j = 0; j < 4; ++j) acc[i][j] = (f32x4){0.f, 0.f, 0.f, 0.f};

    // staging with k-slot XOR swizzle: slot g of row r holds k-group g^((r>>1)&3)
    const int r = tid >> 2;
    const int g = tid & 3;
    const int kg = g ^ ((r >> 1) & 3);
    const bf16* gA0 = Xn + (size_t)(rowA0 + r) * DD + kg * 8;
    const bf16* gA1 = gA0 + (size_t)64 * DD;
    const bf16* gB0 = Xn + (size_t)(rowB0 + r) * DD + kg * 8;
    const bf16* gB1 = gB0 + (size_t)64 * DD;
    bf16* lA0 = As + tid * 8;
    bf16* lA1 = As + 64 * 32 + tid * 8;
    bf16* lB0 = Bs + tid * 8;
    bf16* lB1 = Bs + 64 * 32 + tid * 8;

    const int sw = (lc >> 1) & 3;   // read-side swizzle
    const int slot8 = (lr ^ sw) * 8;

    // prologue: stage 0 into buffer 0
    gl2lds16(gA0, lA0);
    gl2lds16(gA1, lA1);
    gl2lds16(gB0, lB0);
    gl2lds16(gB1, lB1);

    int s = 0;
    for (int k0 = 0; k0 < DD; k0 += 32, s ^= 1) {
        __syncthreads();   // drains vmcnt -> buffer s is ready
        int nk = k0 + 32;
        int noff = (s ^ 1) * 4096;
        if (nk < DD) {     // prefetch next stage into the other buffer
            gl2lds16(gA0 + nk, lA0 + noff);
            gl2lds16(gA1 + nk, lA1 + noff);
            gl2lds16(gB0 + nk, lB0 + noff);
            gl2lds16(gB1 + nk, lB1 + noff);
        }
        const bf16* Ab = As + s * 4096;
        const bf16* Bb = Bs + s * 4096;
        bf16x8 af[4], bfr[4];
#pragma unroll
        for (int mt = 0; mt < 4; ++mt)
            af[mt] = *(const bf16x8*)(Ab + (wm * 64 + mt * 16 + lc) * 32 + slot8);
#pragma unroll
        for (int nt = 0; nt < 4; ++nt)
            bfr[nt] = *(const bf16x8*)(Bb + (wn * 64 + nt * 16 + lc) * 32 + slot8);
#pragma unroll
        for (int mt = 0; mt < 4; ++mt)
#pragma unroll
            for (int nt = 0; nt < 4; ++nt)
                acc[mt][nt] = __builtin_amdgcn_mfma_f32_16x16x32_bf16(
                    af[mt], bfr[nt], acc[mt][nt], 0, 0, 0);
    }

    // Epilogue: S=(c+1)*0.25; mask same-class (incl. diagonal); row+col exp-sums.
    int ycol[4];
#pragma unroll
    for (int nt = 0; nt < 4; ++nt) ycol[nt] = yB[wn * 64 + nt * 16 + lc];
    float colacc[4] = {0.f, 0.f, 0.f, 0.f};
#pragma unroll
    for (int mt = 0; mt < 4; ++mt) {
#pragma unroll
        for (int rr = 0; rr < 4; ++rr) {
            int rloc = wm * 64 + mt * 16 + lr * 4 + rr;  // C row = (lane>>4)*4+reg
            int yrow = yA[rloc];
            float s2 = 0.f;
#pragma unroll
            for (int nt = 0; nt < 4; ++nt) {
                float Sv = (acc[mt][nt][rr] + 1.f) * (0.5f * TAU);
                float e = (ycol[nt] != yrow) ? __expf(Sv) : 0.f;
                s2 += e;
                colacc[nt] += e;
            }
            s2 += __shfl_xor(s2, 1, 16);
            s2 += __shfl_xor(s2, 2, 16);
            s2 += __shfl_xor(s2, 4, 16);
            s2 += __shfl_xor(s2, 8, 16);
            if (lc == 0) atomicAdd(&rowsum[rowA0 + rloc], s2);
        }
    }
    if (!diag) {
#pragma unroll
        for (int nt = 0; nt < 4; ++nt) {
            float cs = colacc[nt];
            cs += __shfl_xor(cs, 16, 64);
            cs += __shfl_xor(cs, 32, 64);
            if (lane < 16) atomicAdd(&rowsum[rowB0 + wn * 64 + nt * 16 + lane], cs);
        }
    }
}

// K3: fused posval + finalize. One wave per row; atomicAdd into out.
__global__ __launch_bounds__(256) void k_tail(const bf16* __restrict__ Xn,
                                              const int* __restrict__ y,
                                              const int* __restrict__ cnt,
                                              const int* __restrict__ mn1,
                                              const int* __restrict__ mn2,
                                              const float* __restrict__ rowsum,
                                              float* __restrict__ out) {
    int w = threadIdx.x >> 6, lane = threadIdx.x & 63;
    int i = blockIdx.x * 4 + w;
    int c = y[i];
    int cc = cnt[c];
    float pv = 0.f;
    if (cc >= 2) {
        int fp = (mn1[c] == i) ? mn2[c] : mn1[c];
        const bf16* xi = Xn + (size_t)i * DD;
        const bf16* xf = Xn + (size_t)fp * DD;
        float dot = 0.f;
#pragma unroll
        for (int q = 0; q < 2; ++q) {
            bf16x8 a = *(const bf16x8*)(xi + q * 512 + lane * 8);
            bf16x8 b = *(const bf16x8*)(xf + q * 512 + lane * 8);
#pragma unroll
            for (int e = 0; e < 8; ++e) dot += (float)a[e] * (float)b[e];
        }
#pragma unroll
        for (int m = 1; m < 64; m <<= 1) dot += __shfl_xor(dot, m, 64);
        pv = (dot + 1.f) * (0.5f * TAU);
    }
    float contrib = logf(rowsum[i] + __expf(pv) + (float)(NN - 2 + cc)) - pv;
    __shared__ float wsum[4];
    if (lane == 0) wsum[w] = contrib;
    __syncthreads();
    if (threadIdx.x == 0)
        atomicAdd(out, (wsum[0] + wsum[1] + wsum[2] + wsum[3]) * (1.f / (float)NN));
}

extern "C" void kernel_launch(void* const* d_in, const int* in_sizes, int n_in,
                              void* d_out, int out_size, void* d_ws, size_t ws_size,
                              hipStream_t stream) {
    const float* X = (const float*)d_in[0];
    const int* y = (const int*)d_in[1];
    float* out = (float*)d_out;

    char* ws = (char*)d_ws;
    bf16* Xn    = (bf16*)ws;                                  // 8 MB
    float* rsum = (float*)(ws + 8 * 1024 * 1024);             // 16 KB
    int* cnt    = (int*)(ws + 8 * 1024 * 1024 + 16 * 1024);
    int* mn1    = (int*)(ws + 8 * 1024 * 1024 + 16 * 1024 + 512);
    int* mn2    = (int*)(ws + 8 * 1024 * 1024 + 16 * 1024 + 1024);

    k_prep<<<dim3(1025), 256, 0, stream>>>(X, Xn, rsum, y, cnt, mn1, mn2, out);
    k_gemm<<<dim3(528), 256, 0, stream>>>(Xn, y, rsum);
    k_tail<<<dim3(NN / 4), 256, 0, stream>>>(Xn, y, cnt, mn1, mn2, rsum, out);
}